// Round 1
// baseline (779.679 us; speedup 1.0000x reference)
//
#include <hip/hip_runtime.h>
#include <hip/hip_bf16.h>

#define BATCH 16
#define T 256
#define DHW 5760  // 3*30*64
#define HPAD 264  // padded bf16 row stride for h in LDS (breaks bank conflicts)
#define XPAD 776  // padded f32 row stride for X=gi+b_hh in LDS

typedef __bf16 bf16x8 __attribute__((ext_vector_type(8)));
typedef float f32x4 __attribute__((ext_vector_type(4)));

// ---------- gate nonlinearities: odd Taylor, args are |x| <~ 0.4 ----------
__device__ __forceinline__ float tanh_poly(float x) {
    float t = x * x;
    float p = fmaf(t, 62.0f / 2835.0f, -17.0f / 315.0f);
    p = fmaf(t, p, 2.0f / 15.0f);
    p = fmaf(t, p, -1.0f / 3.0f);
    p = fmaf(t, p, 1.0f);
    return x * p;
}
__device__ __forceinline__ float sigmoid_poly(float x) {
    return fmaf(0.5f, tanh_poly(0.5f * x), 0.5f);
}

// ---------- kernel A: global average pool (B*T rows of 5760 floats) ----------
__global__ void pool_kernel(const float* __restrict__ x, float* __restrict__ g) {
    const int row = blockIdx.x;  // 0..4095 = b*T + t
    const float4* xr = (const float4*)(x + (size_t)row * DHW);
    float s = 0.0f;
    for (int i = threadIdx.x; i < DHW / 4; i += 256) {
        float4 v = xr[i];
        s += (v.x + v.y) + (v.z + v.w);
    }
    #pragma unroll
    for (int off = 32; off > 0; off >>= 1) s += __shfl_down(s, off, 64);
    __shared__ float red[4];
    const int lane = threadIdx.x & 63, wv = threadIdx.x >> 6;
    if (lane == 0) red[wv] = s;
    __syncthreads();
    if (threadIdx.x == 0) {
        float t = (red[0] + red[1]) + (red[2] + red[3]);
        g[row] = t * (1.0f / (float)DHW);
    }
}

// ---------- kernel B1: mask[b][o] = sum_i g[b][i]*conv_w[o][i][1] + conv_b[o] ----------
__global__ void mask_kernel(const float* __restrict__ g, const float* __restrict__ conv_w,
                            const float* __restrict__ conv_b, float* __restrict__ mask) {
    const int b = blockIdx.x;      // 16
    const int o = threadIdx.x;     // 256
    __shared__ float gs[T];
    gs[o] = g[b * T + o];
    __syncthreads();
    float s = conv_b[o];
    const float* cw = conv_w + (size_t)o * T * 3 + 1;  // middle tap
    #pragma unroll 4
    for (int i = 0; i < T; ++i) s = fmaf(gs[i], cw[i * 3], s);
    mask[b * T + o] = s;
}

// ---------- kernel B2: gi[b][j] = sum_o mask[b][o]*w_ih[j][o] + b_ih[j] ----------
__global__ void gi_kernel(const float* __restrict__ mask, const float* __restrict__ w_ih,
                          const float* __restrict__ b_ih, float* __restrict__ gi) {
    const int b = blockIdx.y;                       // 16
    const int j = blockIdx.x * 256 + threadIdx.x;   // grid.x = 3 -> j in [0,768)
    __shared__ float ms[T];
    ms[threadIdx.x] = mask[b * T + threadIdx.x];
    __syncthreads();
    float s = b_ih[j];
    const float* wr = w_ih + (size_t)j * T;
    #pragma unroll 4
    for (int o = 0; o < T; ++o) s = fmaf(ms[o], wr[o], s);
    gi[b * 768 + j] = s;
}

// ---------- kernel C: 256-step GRU on a single CU, MFMA bf16, weights in regs ----------
// wave w (of 8) owns h-columns [32w, 32w+32); 6 16x16 gh-tiles per wave (r,r,z,z,n,n)
__global__ __launch_bounds__(512, 2) void gru_kernel(
    const float* __restrict__ gi,    // [16][768]
    const float* __restrict__ w_hh,  // [768][256]
    const float* __restrict__ b_hh,  // [768]
    float* __restrict__ out)         // [16][256][256]
{
    __shared__ __align__(16) __bf16 h_lds[BATCH * HPAD];   // 8448 B
    __shared__ float X_lds[BATCH * XPAD];                  // gi + b_hh, 49664 B
    __shared__ float bhn_lds[T];                           // b_hh[512+..], 1 KB

    const int tid = threadIdx.x;
    const int w = tid >> 6;
    const int lane = tid & 63;
    const int l15 = lane & 15;
    const int quad = lane >> 4;
    const int hc = w * 32;  // this wave's h-column base

    int cb[6];
    cb[0] = hc;       cb[1] = hc + 16;
    cb[2] = 256 + hc; cb[3] = 256 + hc + 16;
    cb[4] = 512 + hc; cb[5] = 512 + hc + 16;

    // ---- prologue: load weight B-fragments into registers (bf16) ----
    // B[k][n] fragment: n = lane&15 (row of w_hh), k = quad*8 + j + 32*kc
    bf16x8 bf[6][8];
    #pragma unroll
    for (int t = 0; t < 6; ++t) {
        const float* wr = w_hh + (size_t)(cb[t] + l15) * T + quad * 8;
        #pragma unroll
        for (int kc = 0; kc < 8; ++kc) {
            const float4* p = (const float4*)(wr + kc * 32);
            float4 v0 = p[0], v1 = p[1];
            bf16x8 v;
            v[0] = (__bf16)v0.x; v[1] = (__bf16)v0.y; v[2] = (__bf16)v0.z; v[3] = (__bf16)v0.w;
            v[4] = (__bf16)v1.x; v[5] = (__bf16)v1.y; v[6] = (__bf16)v1.z; v[7] = (__bf16)v1.w;
            bf[t][kc] = v;
        }
    }

    // ---- prologue: X = gi + b_hh (acc init values), bhn = b_hh[512:768] ----
    for (int idx = tid; idx < BATCH * 768; idx += 512) {
        int b = idx / 768, j = idx - b * 768;
        X_lds[b * XPAD + j] = gi[idx] + b_hh[j];
    }
    if (tid < T) bhn_lds[tid] = b_hh[512 + tid];
    for (int idx = tid; idx < BATCH * HPAD; idx += 512) h_lds[idx] = (__bf16)0.0f;

    float hreg[8];  // h_old at [batch=quad*4+i][col=hc+16c+l15], index i*2+c
    #pragma unroll
    for (int q = 0; q < 8; ++q) hreg[q] = 0.0f;

    __syncthreads();

    const __bf16* arow = h_lds + l15 * HPAD + quad * 8;  // A-frag: m=lane&15=batch

    for (int step = 0; step < T; ++step) {
        // acc init: r/z tiles from X (= gi+b_hh), n tiles from b_hh only
        f32x4 acc[6];
        #pragma unroll
        for (int t = 0; t < 4; ++t) {
            const int j = cb[t] + l15;
            #pragma unroll
            for (int i = 0; i < 4; ++i)
                acc[t][i] = X_lds[(quad * 4 + i) * XPAD + j];
        }
        const float bh0 = bhn_lds[hc + l15];
        const float bh1 = bhn_lds[hc + 16 + l15];
        #pragma unroll
        for (int i = 0; i < 4; ++i) { acc[4][i] = bh0; acc[5][i] = bh1; }

        // gh = h @ w_hh^T + (init): 8 K-chunks x 6 tiles
        #pragma unroll
        for (int kc = 0; kc < 8; ++kc) {
            bf16x8 a = *(const bf16x8*)(arow + kc * 32);
            #pragma unroll
            for (int t = 0; t < 6; ++t)
                acc[t] = __builtin_amdgcn_mfma_f32_16x16x32_bf16(a, bf[t][kc], acc[t], 0, 0, 0);
        }

        // gates + state update; lane holds batch=quad*4+i, col=hc+16c+l15
        #pragma unroll
        for (int c = 0; c < 2; ++c) {
            const int col = hc + c * 16 + l15;
            const float bh = c ? bh1 : bh0;
            #pragma unroll
            for (int i = 0; i < 4; ++i) {
                const int batch = quad * 4 + i;
                const float xr = acc[c][i];          // gi_r + b_hh_r + h.Wr
                const float xz = acc[2 + c][i];      // gi_z + b_hh_z + h.Wz
                const float ghn = acc[4 + c][i];     // b_hh_n + h.Wn
                const float gin = X_lds[batch * XPAD + 512 + col] - bh;  // gi_n
                const float r = sigmoid_poly(xr);
                const float z = sigmoid_poly(xz);
                const float n = tanh_poly(fmaf(r, ghn, gin));
                const float h = hreg[i * 2 + c];
                const float hn = fmaf(z, h - n, n);
                hreg[i * 2 + c] = hn;
            }
        }

        __syncthreads();  // all A-frag reads of old h done

        #pragma unroll
        for (int c = 0; c < 2; ++c) {
            const int col = hc + c * 16 + l15;
            #pragma unroll
            for (int i = 0; i < 4; ++i) {
                const int batch = quad * 4 + i;
                const float hn = hreg[i * 2 + c];
                h_lds[batch * HPAD + col] = (__bf16)hn;
                out[((size_t)batch * T + step) * T + col] = hn;
            }
        }

        __syncthreads();  // new h visible before next step's A-frag reads
    }
}

extern "C" void kernel_launch(void* const* d_in, const int* in_sizes, int n_in,
                              void* d_out, int out_size, void* d_ws, size_t ws_size,
                              hipStream_t stream) {
    const float* x      = (const float*)d_in[0];
    const float* conv_w = (const float*)d_in[1];
    const float* conv_b = (const float*)d_in[2];
    const float* w_ih   = (const float*)d_in[3];
    const float* w_hh   = (const float*)d_in[4];
    const float* b_ih   = (const float*)d_in[5];
    const float* b_hh   = (const float*)d_in[6];
    float* out = (float*)d_out;

    float* ws   = (float*)d_ws;
    float* g    = ws;            // 4096
    float* mask = ws + 4096;     // 4096
    float* gi   = ws + 8192;     // 12288

    pool_kernel<<<BATCH * T, 256, 0, stream>>>(x, g);
    mask_kernel<<<BATCH, 256, 0, stream>>>(g, conv_w, conv_b, mask);
    gi_kernel<<<dim3(3, BATCH), 256, 0, stream>>>(mask, w_ih, b_ih, gi);
    gru_kernel<<<1, 512, 0, stream>>>(gi, w_hh, b_hh, out);
}

// Round 2
// 732.878 us; speedup vs baseline: 1.0639x; 1.0639x over previous
//
#include <hip/hip_runtime.h>
#include <hip/hip_bf16.h>

#define BATCH 16
#define T 256
#define DHW 5760  // 3*30*64
#define HPAD 264  // padded bf16 row stride for h in LDS

typedef __bf16 bf16x8 __attribute__((ext_vector_type(8)));
typedef float f32x4 __attribute__((ext_vector_type(4)));

// ---------- gate nonlinearities: odd Taylor, |arg| <~ 0.5 ----------
__device__ __forceinline__ float tanh7(float x) {
    float t = x * x;
    float p = fmaf(t, fmaf(t, fmaf(t, -17.0f / 315.0f, 2.0f / 15.0f), -1.0f / 3.0f), 1.0f);
    return x * p;
}
__device__ __forceinline__ float sigm(float x) {  // sigmoid(x) = 0.5 + 0.5*tanh(x/2), deg-5 (|x/2|<0.3)
    float u = 0.5f * x;
    float t = u * u;
    float p = fmaf(t, fmaf(t, 2.0f / 15.0f, -1.0f / 3.0f), 1.0f);
    return fmaf(0.5f * u, p, 0.5f);
}

// ---------- kernel A: global average pool (B*T rows of 5760 floats) ----------
__global__ void pool_kernel(const float* __restrict__ x, float* __restrict__ g) {
    const int row = blockIdx.x;  // b*T + t
    const float4* xr = (const float4*)(x + (size_t)row * DHW);
    float s = 0.0f;
    for (int i = threadIdx.x; i < DHW / 4; i += 256) {
        float4 v = xr[i];
        s += (v.x + v.y) + (v.z + v.w);
    }
    #pragma unroll
    for (int off = 32; off > 0; off >>= 1) s += __shfl_down(s, off, 64);
    __shared__ float red[4];
    const int lane = threadIdx.x & 63, wv = threadIdx.x >> 6;
    if (lane == 0) red[wv] = s;
    __syncthreads();
    if (threadIdx.x == 0) {
        float t = (red[0] + red[1]) + (red[2] + red[3]);
        g[row] = t * (1.0f / (float)DHW);
    }
}

// ---------- kernel B1: block per output row o, coalesced weights, shfl-reduce ----------
__global__ void mask_kernel(const float* __restrict__ g, const float* __restrict__ conv_w,
                            const float* __restrict__ conv_b, float* __restrict__ mask) {
    const int o = blockIdx.x;       // 256
    const int i = threadIdx.x;      // 256
    const int lane = i & 63, wv = i >> 6;
    const float wt = conv_w[o * 768 + 3 * i + 1];  // middle tap
    __shared__ float part[16][4];
    #pragma unroll 4
    for (int b = 0; b < 16; ++b) {
        float v = wt * g[b * 256 + i];
        #pragma unroll
        for (int off = 32; off > 0; off >>= 1) v += __shfl_down(v, off, 64);
        if (lane == 0) part[b][wv] = v;
    }
    __syncthreads();
    if (i < 16) {
        mask[i * 256 + o] = part[i][0] + part[i][1] + part[i][2] + part[i][3] + conv_b[o];
    }
}

// ---------- kernel B2: block per output row j, coalesced weights, shfl-reduce ----------
__global__ void gi_kernel(const float* __restrict__ mask, const float* __restrict__ w_ih,
                          const float* __restrict__ b_ih, float* __restrict__ gi) {
    const int j = blockIdx.x;       // 768
    const int o = threadIdx.x;      // 256
    const int lane = o & 63, wv = o >> 6;
    const float wt = w_ih[j * 256 + o];
    __shared__ float part[16][4];
    #pragma unroll 4
    for (int b = 0; b < 16; ++b) {
        float v = wt * mask[b * 256 + o];
        #pragma unroll
        for (int off = 32; off > 0; off >>= 1) v += __shfl_down(v, off, 64);
        if (lane == 0) part[b][wv] = v;
    }
    __syncthreads();
    if (o < 16) gi[o * 768 + j] = part[o][0] + part[o][1] + part[o][2] + part[o][3] + b_ih[j];
}

// ---------- kernel C: 256-step GRU, single CU, 16 waves (4/SIMD), 3 tiles/wave ----------
// wave w owns h-columns [16w, 16w+16); one 16x16 tile per gate (r,z,n)
__global__ __launch_bounds__(1024, 1) void gru_kernel(
    const float* __restrict__ gi,    // [16][768]
    const float* __restrict__ w_hh,  // [768][256]
    const float* __restrict__ b_hh,  // [768]
    float* __restrict__ out)         // [16][256][256]
{
    __shared__ __align__(16) __bf16 hb0[BATCH * HPAD];  // 8448 B
    __shared__ __align__(16) __bf16 hb1[BATCH * HPAD];  // 8448 B
    __shared__ __align__(16) float Xr[4096];            // packed r C-init, 16 KB
    __shared__ __align__(16) float Xz[4096];            // packed z C-init, 16 KB

    const int tid = threadIdx.x;
    const int w = tid >> 6;
    const int lane = tid & 63;
    const int l15 = lane & 15;
    const int quad = lane >> 4;
    const int col = 16 * w + l15;   // this lane's h-column
    const int b0 = quad * 4;        // this lane's batch base (C rows)

    // ---- weights: 3 B-frag tiles; B[k][n]: n=l15 -> w_hh row (256g+col), k=quad*8+j+32kc
    bf16x8 bw[3][8];
    #pragma unroll
    for (int g = 0; g < 3; ++g) {
        const float* wr = w_hh + (size_t)(g * 256 + col) * T + quad * 8;
        #pragma unroll
        for (int kc = 0; kc < 8; ++kc) {
            const float4* p = (const float4*)(wr + kc * 32);
            float4 v0 = p[0], v1 = p[1];
            bf16x8 v;
            v[0] = (__bf16)v0.x; v[1] = (__bf16)v0.y; v[2] = (__bf16)v0.z; v[3] = (__bf16)v0.w;
            v[4] = (__bf16)v1.x; v[5] = (__bf16)v1.y; v[6] = (__bf16)v1.z; v[7] = (__bf16)v1.w;
            bw[g][kc] = v;
        }
    }

    // ---- per-lane constants: C-init for r,z packed to LDS (read as b128 each step);
    //      gi_n and b_hh_n stay in 5 registers
    {
        f32x4 vr, vz;
        #pragma unroll
        for (int i = 0; i < 4; ++i) {
            const float* gb = gi + (size_t)(b0 + i) * 768;
            vr[i] = gb[col] + b_hh[col];
            vz[i] = gb[256 + col] + b_hh[256 + col];
        }
        *(f32x4*)&Xr[tid * 4] = vr;
        *(f32x4*)&Xz[tid * 4] = vz;
    }
    const float bn = b_hh[512 + col];
    f32x4 gn;
    #pragma unroll
    for (int i = 0; i < 4; ++i) gn[i] = gi[(size_t)(b0 + i) * 768 + 512 + col];

    for (int idx = tid; idx < BATCH * HPAD; idx += 1024) {
        hb0[idx] = (__bf16)0.0f;
        hb1[idx] = (__bf16)0.0f;
    }

    const int aoff = l15 * HPAD + quad * 8;  // A-frag element offset: m=l15(batch), k=quad*8+j
    const int hoff = b0 * HPAD + col;        // h read/write element offset
    unsigned ooff = (unsigned)b0 * 65536u + (unsigned)col;

    __syncthreads();

    auto gru_step = [&](const __bf16* __restrict__ curb, __bf16* __restrict__ nxtb) {
        f32x4 accr = *(const f32x4*)&Xr[tid * 4];          // gi_r + b_hh_r
        f32x4 accz = *(const f32x4*)&Xz[tid * 4];          // gi_z + b_hh_z
        f32x4 accn = {0.0f, 0.0f, 0.0f, 0.0f};
        f32x4 hold;
        #pragma unroll
        for (int i = 0; i < 4; ++i) hold[i] = (float)curb[hoff + i * HPAD];

        const __bf16* ar = curb + aoff;
        #pragma unroll
        for (int kc = 0; kc < 8; ++kc) {
            bf16x8 a = *(const bf16x8*)(ar + kc * 32);
            accr = __builtin_amdgcn_mfma_f32_16x16x32_bf16(a, bw[0][kc], accr, 0, 0, 0);
            accz = __builtin_amdgcn_mfma_f32_16x16x32_bf16(a, bw[1][kc], accz, 0, 0, 0);
            accn = __builtin_amdgcn_mfma_f32_16x16x32_bf16(a, bw[2][kc], accn, 0, 0, 0);
        }

        #pragma unroll
        for (int i = 0; i < 4; ++i) {
            float r = sigm(accr[i]);
            float z = sigm(accz[i]);
            float n = tanh7(fmaf(r, accn[i] + bn, gn[i]));   // gi_n + r*(h.Wn + b_hh_n)
            float hn = fmaf(z, hold[i] - n, n);              // (1-z)n + z*h
            nxtb[hoff + i * HPAD] = (__bf16)hn;
            out[ooff + (unsigned)i * 65536u] = hn;
        }
        ooff += 256u;
        __syncthreads();
    };

    for (int s = 0; s < T; s += 2) {
        gru_step(hb0, hb1);
        gru_step(hb1, hb0);
    }
}

extern "C" void kernel_launch(void* const* d_in, const int* in_sizes, int n_in,
                              void* d_out, int out_size, void* d_ws, size_t ws_size,
                              hipStream_t stream) {
    const float* x      = (const float*)d_in[0];
    const float* conv_w = (const float*)d_in[1];
    const float* conv_b = (const float*)d_in[2];
    const float* w_ih   = (const float*)d_in[3];
    const float* w_hh   = (const float*)d_in[4];
    const float* b_ih   = (const float*)d_in[5];
    const float* b_hh   = (const float*)d_in[6];
    float* out = (float*)d_out;

    float* ws   = (float*)d_ws;
    float* g    = ws;            // 4096
    float* mask = ws + 4096;     // 4096
    float* gi   = ws + 8192;     // 12288

    pool_kernel<<<BATCH * T, 256, 0, stream>>>(x, g);
    mask_kernel<<<T, 256, 0, stream>>>(g, conv_w, conv_b, mask);
    gi_kernel<<<3 * T, 256, 0, stream>>>(mask, w_ih, b_ih, gi);
    gru_kernel<<<1, 1024, 0, stream>>>(gi, w_hh, b_hh, out);
}